// Round 2
// baseline (447.708 us; speedup 1.0000x reference)
//
#include <hip/hip_runtime.h>
#include <hip/hip_bf16.h>
#include <stdint.h>
#include <stddef.h>

typedef __bf16 bf16_t;
typedef __bf16 bf16x8 __attribute__((ext_vector_type(8)));
typedef float  f32x4  __attribute__((ext_vector_type(4)));

#define NN 1024
#define H  128

// ---------------- We fp32 -> bf16 ----------------
__global__ void k_cvt_we(const float* __restrict__ src, bf16_t* __restrict__ dst) {
    int i = blockIdx.x * 256 + threadIdx.x;
    if (i < H * H) dst[i] = (bf16_t)src[i];
}

// ---------------- f_i = node @ Wi^T, f_j = node @ Wj^T (fp32 compute, bf16 store) ----------------
__global__ void k_proj(const float* __restrict__ node,
                       const float* __restrict__ Wi,
                       const float* __restrict__ Wj,
                       bf16_t* __restrict__ fi,
                       bf16_t* __restrict__ fj) {
    __shared__ float nrow[H];
    const int row = blockIdx.x;       // 0..1023
    const int t   = threadIdx.x;      // 0..255
    const int h   = t & (H - 1);
    const int sel = t >> 7;           // 0 -> f_i, 1 -> f_j
    if (t < H) nrow[t] = node[(size_t)row * H + t];
    __syncthreads();
    const float* w = (sel ? Wj : Wi) + (size_t)h * H;
    float acc = 0.f;
    #pragma unroll
    for (int k4 = 0; k4 < H / 4; ++k4) {
        f32x4 wv = *(const f32x4*)(w + k4 * 4);
        f32x4 nv = *(const f32x4*)(&nrow[k4 * 4]);
        acc += nv[0] * wv[0] + nv[1] * wv[1] + nv[2] * wv[2] + nv[3] * wv[3];
    }
    bf16_t* dst = sel ? fj : fi;
    dst[(size_t)row * H + h] = (bf16_t)acc;
}

// ---------------- dots[i][j] = f_i[i] . f_j[j]  (bf16 MFMA, fp32 out) ----------------
// grid = 64 blocks: 8x8 tiles of 128x128; block = 256 thr (4 waves, 32 rows each)
__global__ __launch_bounds__(256, 4)
void k_dots(const bf16_t* __restrict__ fi,
            const bf16_t* __restrict__ fj,
            float* __restrict__ dots) {
    const int t    = threadIdx.x;
    const int wave = t >> 6;
    const int lane = t & 63;
    const int l15  = lane & 15;
    const int g    = lane >> 4;

    const int bm    = blockIdx.x >> 3;
    const int bn    = blockIdx.x & 7;
    const int ibase = bm * 128 + wave * 32;
    const int jbase = bn * 128;

    f32x4 acc[2][8];
    #pragma unroll
    for (int mf = 0; mf < 2; ++mf)
        #pragma unroll
        for (int nt = 0; nt < 8; ++nt)
            acc[mf][nt] = (f32x4){0.f, 0.f, 0.f, 0.f};

    const bf16_t* a0 = fi + (size_t)(ibase +  0 + l15) * H + g * 8;
    const bf16_t* a1 = fi + (size_t)(ibase + 16 + l15) * H + g * 8;

    #pragma unroll
    for (int kst = 0; kst < 4; ++kst) {
        bf16x8 af0 = *(const bf16x8*)(a0 + kst * 32);
        bf16x8 af1 = *(const bf16x8*)(a1 + kst * 32);
        #pragma unroll
        for (int nt = 0; nt < 8; ++nt) {
            bf16x8 bf = *(const bf16x8*)(fj + (size_t)(jbase + nt * 16 + l15) * H + kst * 32 + g * 8);
            acc[0][nt] = __builtin_amdgcn_mfma_f32_16x16x32_bf16(af0, bf, acc[0][nt], 0, 0, 0);
            acc[1][nt] = __builtin_amdgcn_mfma_f32_16x16x32_bf16(af1, bf, acc[1][nt], 0, 0, 0);
        }
    }

    #pragma unroll
    for (int mf = 0; mf < 2; ++mf) {
        const int rbase = ibase + mf * 16 + g * 4;
        #pragma unroll
        for (int r = 0; r < 4; ++r) {
            #pragma unroll
            for (int nt = 0; nt < 8; ++nt)
                dots[(size_t)(rbase + r) * NN + jbase + nt * 16 + l15] = acc[mf][nt][r];
        }
    }
}

// ---------------- main: out = relu(edge @ We^T + be + dots[e]) ----------------
// Swapped-operand MFMA: acc = mfma(We_frag, edge_frag) so D.row = out column,
// D.col = edge row -> each lane's 4 acc regs are 4 consecutive out floats
// (coalesced dwordx4 stores). 16 rows/wave, 64 rows/block, grid = 16384.
__global__ __launch_bounds__(256)
void k_main(const float* __restrict__ edge,   // [1M][128] fp32
            const bf16_t* __restrict__ web,   // [128][128] bf16 (row n, col k)
            const float* __restrict__ be,     // [128]
            const float* __restrict__ dots,   // [1M]
            float* __restrict__ out) {        // [1M][128] fp32
    const int t    = threadIdx.x;
    const int wave = t >> 6;
    const int lane = t & 63;
    const int l15  = lane & 15;
    const int g    = lane >> 4;

    const size_t mrow = (size_t)blockIdx.x * 64 + wave * 16 + l15;  // edge row of this lane
    const float* ap = edge + mrow * H + g * 8;

    // Hoist all 8 edge loads (256 B/thread) before any compute: 8 outstanding
    // HBM loads/wave for latency hiding.
    f32x4 u[8];
    #pragma unroll
    for (int kk = 0; kk < 4; ++kk) {
        u[2 * kk]     = *(const f32x4*)(ap + kk * 32);
        u[2 * kk + 1] = *(const f32x4*)(ap + kk * 32 + 4);
    }

    f32x4 acc[8];
    #pragma unroll
    for (int nt = 0; nt < 8; ++nt) acc[nt] = (f32x4){0.f, 0.f, 0.f, 0.f};

    const bf16_t* wp = web + (size_t)l15 * H + g * 8;

    #pragma unroll
    for (int kk = 0; kk < 4; ++kk) {
        bf16x8 bfrag;
        #pragma unroll
        for (int i = 0; i < 4; ++i) {
            bfrag[i]     = (bf16_t)u[2 * kk][i];
            bfrag[i + 4] = (bf16_t)u[2 * kk + 1][i];
        }
        #pragma unroll
        for (int nt = 0; nt < 8; ++nt) {
            bf16x8 afrag = *(const bf16x8*)(wp + (size_t)(nt * 16) * H + kk * 32);
            acc[nt] = __builtin_amdgcn_mfma_f32_16x16x32_bf16(afrag, bfrag, acc[nt], 0, 0, 0);
        }
    }

    const float dv = dots[mrow];
    float* op = out + mrow * H;

    #pragma unroll
    for (int nt = 0; nt < 8; ++nt) {
        f32x4 bv = *(const f32x4*)(be + nt * 16 + g * 4);
        f32x4 v;
        #pragma unroll
        for (int r = 0; r < 4; ++r)
            v[r] = fmaxf(acc[nt][r] + bv[r] + dv, 0.f);
        __builtin_nontemporal_store(v, (f32x4*)(op + nt * 16 + g * 4));
    }
}

extern "C" void kernel_launch(void* const* d_in, const int* in_sizes, int n_in,
                              void* d_out, int out_size, void* d_ws, size_t ws_size,
                              hipStream_t stream) {
    const float* node = (const float*)d_in[0];
    const float* edge = (const float*)d_in[1];
    const float* We   = (const float*)d_in[2];
    const float* be   = (const float*)d_in[3];
    const float* Wi   = (const float*)d_in[4];
    const float* Wj   = (const float*)d_in[5];
    float* out = (float*)d_out;

    char* w = (char*)d_ws;
    bf16_t* fi_bf = (bf16_t*)w;                              // 256 KB
    bf16_t* fj_bf = (bf16_t*)(w + (256 << 10));              // 256 KB
    float*  dots  = (float*)(w + (512 << 10));               // 4 MB
    bf16_t* web   = (bf16_t*)(w + (512 << 10) + (4 << 20));  // 32 KB

    k_cvt_we<<<(H * H + 255) / 256, 256, 0, stream>>>(We, web);
    k_proj<<<NN, 256, 0, stream>>>(node, Wi, Wj, fi_bf, fj_bf);
    k_dots<<<64, 256, 0, stream>>>(fi_bf, fj_bf, dots);
    k_main<<<(NN * NN) / 64, 256, 0, stream>>>(edge, web, be, dots, out);
}

// Round 3
// 244.520 us; speedup vs baseline: 1.8310x; 1.8310x over previous
//
#include <hip/hip_runtime.h>
#include <hip/hip_bf16.h>
#include <stdint.h>
#include <stddef.h>

typedef __bf16 bf16_t;
typedef __bf16 bf16x8 __attribute__((ext_vector_type(8)));
typedef float  f32x4  __attribute__((ext_vector_type(4)));

#define NN 1024
#define H  128
#define TILES 16384   // 1M rows / 64
#define GRID  2048    // 8 tiles per block

// ---------------- We fp32 -> bf16 ----------------
__global__ void k_cvt_we(const float* __restrict__ src, bf16_t* __restrict__ dst) {
    int i = blockIdx.x * 256 + threadIdx.x;
    if (i < H * H) dst[i] = (bf16_t)src[i];
}

// ---------------- f_i = node @ Wi^T, f_j = node @ Wj^T ----------------
__global__ void k_proj(const float* __restrict__ node,
                       const float* __restrict__ Wi,
                       const float* __restrict__ Wj,
                       bf16_t* __restrict__ fi,
                       bf16_t* __restrict__ fj) {
    __shared__ float nrow[H];
    const int row = blockIdx.x;
    const int t   = threadIdx.x;
    const int h   = t & (H - 1);
    const int sel = t >> 7;
    if (t < H) nrow[t] = node[(size_t)row * H + t];
    __syncthreads();
    const float* w = (sel ? Wj : Wi) + (size_t)h * H;
    float acc = 0.f;
    #pragma unroll
    for (int k4 = 0; k4 < H / 4; ++k4) {
        f32x4 wv = *(const f32x4*)(w + k4 * 4);
        f32x4 nv = *(const f32x4*)(&nrow[k4 * 4]);
        acc += nv[0] * wv[0] + nv[1] * wv[1] + nv[2] * wv[2] + nv[3] * wv[3];
    }
    bf16_t* dst = sel ? fj : fi;
    dst[(size_t)row * H + h] = (bf16_t)acc;
}

// ---------------- dots[i][j] = f_i[i] . f_j[j] ----------------
__global__ __launch_bounds__(256, 4)
void k_dots(const bf16_t* __restrict__ fi,
            const bf16_t* __restrict__ fj,
            float* __restrict__ dots) {
    const int t    = threadIdx.x;
    const int wave = t >> 6;
    const int lane = t & 63;
    const int l15  = lane & 15;
    const int g    = lane >> 4;

    const int bm    = blockIdx.x >> 3;
    const int bn    = blockIdx.x & 7;
    const int ibase = bm * 128 + wave * 32;
    const int jbase = bn * 128;

    f32x4 acc[2][8];
    #pragma unroll
    for (int mf = 0; mf < 2; ++mf)
        #pragma unroll
        for (int nt = 0; nt < 8; ++nt)
            acc[mf][nt] = (f32x4){0.f, 0.f, 0.f, 0.f};

    const bf16_t* a0 = fi + (size_t)(ibase +  0 + l15) * H + g * 8;
    const bf16_t* a1 = fi + (size_t)(ibase + 16 + l15) * H + g * 8;

    #pragma unroll
    for (int kst = 0; kst < 4; ++kst) {
        bf16x8 af0 = *(const bf16x8*)(a0 + kst * 32);
        bf16x8 af1 = *(const bf16x8*)(a1 + kst * 32);
        #pragma unroll
        for (int nt = 0; nt < 8; ++nt) {
            bf16x8 bf = *(const bf16x8*)(fj + (size_t)(jbase + nt * 16 + l15) * H + kst * 32 + g * 8);
            acc[0][nt] = __builtin_amdgcn_mfma_f32_16x16x32_bf16(af0, bf, acc[0][nt], 0, 0, 0);
            acc[1][nt] = __builtin_amdgcn_mfma_f32_16x16x32_bf16(af1, bf, acc[1][nt], 0, 0, 0);
        }
    }

    #pragma unroll
    for (int mf = 0; mf < 2; ++mf) {
        const int rbase = ibase + mf * 16 + g * 4;
        #pragma unroll
        for (int r = 0; r < 4; ++r) {
            #pragma unroll
            for (int nt = 0; nt < 8; ++nt)
                dots[(size_t)(rbase + r) * NN + jbase + nt * 16 + l15] = acc[mf][nt][r];
        }
    }
}

// ---------------- async global -> LDS (16B per lane, dest = wave base + lane*16) ----------------
__device__ __forceinline__ void gl_lds16(const float* g, float* l) {
    __builtin_amdgcn_global_load_lds(
        (const __attribute__((address_space(1))) unsigned int*)g,
        (__attribute__((address_space(3))) unsigned int*)l,
        16, 0, 0);
}

// ---------------- main: out = relu(edge @ We^T + be + dots[row]) ----------------
// Wave-self-contained double-buffered stream: each wave owns 16 rows/tile,
// stages them contiguously via global_load_lds, counted vmcnt(8) (no barriers
// in loop). Web (We bf16) lives in 128 VGPRs, loaded once. Swapped-operand
// MFMA -> coalesced dwordx4 stores.
__global__ __launch_bounds__(256)
void k_main(const float* __restrict__ edge,   // [1M][128] fp32
            const bf16_t* __restrict__ web,   // [128][128] bf16
            const float* __restrict__ be,     // [128]
            const float* __restrict__ dots,   // [1M]
            float* __restrict__ out) {        // [1M][128] fp32
    __shared__ float lds[2][64][H];   // 64 KB, wave w owns rows [16w,16w+16)
    __shared__ float lbias[H];

    const int t    = threadIdx.x;
    const int wave = t >> 6;
    const int lane = t & 63;
    const int l15  = lane & 15;
    const int g    = lane >> 4;

    // bias -> LDS (one load + barrier, before any async staging)
    if (t < H) lbias[t] = be[t];
    __syncthreads();

    const int tile0 = blockIdx.x;

    // prologue: stage tile0 into buf 0 (wave-private region, contiguous src)
    {
        const float* src = edge + ((size_t)tile0 * 64 + wave * 16) * H + lane * 4;
        float* dst = &lds[0][wave * 16][0];
        #pragma unroll
        for (int i = 0; i < 8; ++i)
            gl_lds16(src + i * 256, dst + i * 256);
    }

    // web fragments (A operand), whole matrix in regs: wfr[nt][kk]
    bf16x8 wfr[8][4];
    {
        const bf16_t* wp = web + (size_t)l15 * H + g * 8;
        #pragma unroll
        for (int nt = 0; nt < 8; ++nt)
            #pragma unroll
            for (int kk = 0; kk < 4; ++kk)
                wfr[nt][kk] = *(const bf16x8*)(wp + (size_t)(nt * 16) * H + kk * 32);
    }

    // dots for this lane's row in each of the 8 tiles
    float dvv[8];
    #pragma unroll
    for (int k = 0; k < 8; ++k)
        dvv[k] = dots[(size_t)(tile0 + k * GRID) * 64 + wave * 16 + l15];

    int cur = 0;
    #pragma unroll 1
    for (int k = 0; k < 8; ++k) {
        const size_t tile = (size_t)tile0 + (size_t)k * GRID;

        // current buffer staged: everything older than the last 8 vmem ops
        // (= previous iteration's 8 stores) has completed.
        asm volatile("s_waitcnt vmcnt(8)" ::: "memory");
        __builtin_amdgcn_sched_barrier(0);

        // stage next tile into the other buffer (stays in flight across MFMA)
        if (k < 7) {
            const float* src = edge + ((tile + GRID) * 64 + wave * 16) * H + lane * 4;
            float* dst = &lds[cur ^ 1][wave * 16][0];
            #pragma unroll
            for (int i = 0; i < 8; ++i)
                gl_lds16(src + i * 256, dst + i * 256);
        }

        // acc init = bias + dot (bias from LDS: broadcast reads, conflict-free)
        const float dv = dvv[k];
        f32x4 acc[8];
        #pragma unroll
        for (int nt = 0; nt < 8; ++nt) {
            f32x4 bvv = *(const f32x4*)(&lbias[nt * 16 + g * 4]);
            #pragma unroll
            for (int r = 0; r < 4; ++r) acc[nt][r] = bvv[r] + dv;
        }

        const float* lrow = &lds[cur][wave * 16 + l15][g * 8];
        #pragma unroll
        for (int kk = 0; kk < 4; ++kk) {
            f32x4 u0 = *(const f32x4*)(lrow + kk * 32);
            f32x4 u1 = *(const f32x4*)(lrow + kk * 32 + 4);
            bf16x8 bfrag;
            #pragma unroll
            for (int i2 = 0; i2 < 4; ++i2) {
                bfrag[i2]     = (bf16_t)u0[i2];
                bfrag[i2 + 4] = (bf16_t)u1[i2];
            }
            #pragma unroll
            for (int nt = 0; nt < 8; ++nt)
                acc[nt] = __builtin_amdgcn_mfma_f32_16x16x32_bf16(wfr[nt][kk], bfrag, acc[nt], 0, 0, 0);
        }

        // coalesced stores: 16 rows x 64B per instruction
        float* op = out + (tile * 64 + wave * 16 + l15) * H + g * 4;
        #pragma unroll
        for (int nt = 0; nt < 8; ++nt) {
            f32x4 v;
            #pragma unroll
            for (int r = 0; r < 4; ++r) v[r] = fmaxf(acc[nt][r], 0.f);
            *(f32x4*)(op + nt * 16) = v;
        }

        cur ^= 1;
    }
}

extern "C" void kernel_launch(void* const* d_in, const int* in_sizes, int n_in,
                              void* d_out, int out_size, void* d_ws, size_t ws_size,
                              hipStream_t stream) {
    const float* node = (const float*)d_in[0];
    const float* edge = (const float*)d_in[1];
    const float* We   = (const float*)d_in[2];
    const float* be   = (const float*)d_in[3];
    const float* Wi   = (const float*)d_in[4];
    const float* Wj   = (const float*)d_in[5];
    float* out = (float*)d_out;

    char* w = (char*)d_ws;
    bf16_t* fi_bf = (bf16_t*)w;                              // 256 KB
    bf16_t* fj_bf = (bf16_t*)(w + (256 << 10));              // 256 KB
    float*  dots  = (float*)(w + (512 << 10));               // 4 MB
    bf16_t* web   = (bf16_t*)(w + (512 << 10) + (4 << 20));  // 32 KB

    k_cvt_we<<<(H * H + 255) / 256, 256, 0, stream>>>(We, web);
    k_proj<<<NN, 256, 0, stream>>>(node, Wi, Wj, fi_bf, fj_bf);
    k_dots<<<64, 256, 0, stream>>>(fi_bf, fj_bf, dots);
    k_main<<<GRID, 256, 0, stream>>>(edge, web, be, dots, out);
}